// Round 11
// baseline (102.924 us; speedup 1.0000x reference)
//
#include <hip/hip_runtime.h>
#include <hip/hip_bf16.h>

#define BSZ 32
#define CIN 128
#define CD 64
#define HH 64
#define WW 64
#define PLANE (HH * WW)
#define NPIX (BSZ * HH * WW)
#define NB 8
#define BN_EPS 1e-5f

typedef __attribute__((ext_vector_type(8))) short short8v;
typedef __attribute__((ext_vector_type(4))) float f32x4;
typedef __attribute__((ext_vector_type(4))) unsigned int u32x4;

static __device__ __forceinline__ short f2bf(float f) {
    __hip_bfloat16 h = __float2bfloat16(f);
    return __builtin_bit_cast(short, h);
}
// packed bf16 convert: dst.lo16 = bf16(lo), dst.hi16 = bf16(hi) (RNE)
static __device__ __forceinline__ unsigned int cvtpk(float lo, float hi) {
    unsigned int r;
    asm("v_cvt_pk_bf16_f32 %0, %1, %2" : "=v"(r) : "v"(lo), "v"(hi));
    return r;
}
// closed-form uniform cubic B-spline 8-slot window (4 nonzero bf16 weights),
// placed by dword-select — identical math to rounds 6-10 (verified).
static __device__ __forceinline__ u32x4 basisD(float v) {
    const float tt = (v + 2.2f) * 2.5f;
    const float fi = floorf(tt);
    const int i0 = (int)fi;
    const float u = tt - fi;
    const bool inr = (tt >= 0.0f) && (tt < 11.0f);
    const float u2 = u * u, u3 = u2 * u;
    const float t1 = 1.f - u;
    const float w0 = (1.f / 6.f) * t1 * t1 * t1;
    const float w3 = (1.f / 6.f) * u3;
    const float w1 = fmaf(0.5f, u3, 2.f / 3.f) - u2;
    const float w2 = 1.f - w0 - w1 - w3;
    const unsigned W01 = cvtpk(w0, w1);
    const unsigned W23 = cvtpk(w2, w3);
    const int q0 = i0 - 3;
    int a = q0 >> 1;
    const int bpar = q0 & 1;
    if (!inr) a = 100;
    const unsigned A1c = (W01 >> 16) | (W23 << 16);
    const unsigned C0 = bpar ? (W01 << 16) : W01;
    const unsigned C1 = bpar ? A1c : W23;
    const unsigned C2 = bpar ? (W23 >> 16) : 0u;
    u32x4 D;
    D.x = (a == 0) ? C0 : (a == -1) ? C1 : (a == -2) ? C2 : 0u;
    D.y = (a == 1) ? C0 : (a == 0) ? C1 : (a == -1) ? C2 : 0u;
    D.z = (a == 2) ? C0 : (a == 1) ? C1 : (a == 0) ? C2 : 0u;
    D.w = (a == 3) ? C0 : (a == 2) ? C1 : (a == 1) ? C2 : 0u;
    return D;
}
// rebuild tile0/tile1 bf16 A-frags from a [ch][17] pair pad
static __device__ __forceinline__ void gather_frags(
    const unsigned* __restrict__ pad, int s3, int hi, int m,
    short8v& f0, short8v& f1)
{
    unsigned q[8];
#pragma unroll
    for (int e = 0; e < 8; ++e) q[e] = pad[(s3 * 32 + 8 * hi + e) * 17 + m];
#pragma unroll
    for (int qi = 0; qi < 4; ++qi) {
        ((unsigned*)&f0)[qi] = (q[2 * qi] & 0xffffu) | (q[2 * qi + 1] << 16);
        ((unsigned*)&f1)[qi] = (q[2 * qi] >> 16) | (q[2 * qi + 1] & 0xffff0000u);
    }
}

// ---------------------------------------------------------------------------
// K0: prepack all matmul weights into MFMA B-fragment order (bf16) + fold BN.
// Fragment layout (verified round 2): element ((s*4+c)*64+l)*8+e holds
// W[k = s*32 + (l>>4)*8 + e][j = c*16 + (l&15)].
// ---------------------------------------------------------------------------
__global__ __launch_bounds__(256) void k_prep(
    const float* __restrict__ coef, const float* __restrict__ ssp,
    const float* __restrict__ sb, const float* __restrict__ f2w,
    const float* __restrict__ reduce_w, const float* __restrict__ g_w,
    const float* __restrict__ dw_g, const float* __restrict__ dw_beta,
    const float* __restrict__ dw_m, const float* __restrict__ dw_v,
    const float* __restrict__ dw_b, const float* __restrict__ g_g,
    const float* __restrict__ g_beta, const float* __restrict__ g_m,
    const float* __restrict__ g_v, const float* __restrict__ g_b,
    short* __restrict__ W1f, short* __restrict__ W2f,
    short* __restrict__ WRf, short* __restrict__ WGf,
    float* __restrict__ cbuf)
{
    const int idx = blockIdx.x * 256 + threadIdx.x;
    if (idx < 36864) {
        const int e = idx & 7, l = (idx >> 3) & 63, c = (idx >> 9) & 3, s = idx >> 11;
        const int k = s * 32 + ((l >> 4) << 3) + e;
        const int j = (c << 4) + (l & 15);
        float v;
        if (k < 512) {
            const int i = k >> 3, t = k & 7;
            v = coef[(i * 64 + j) * 8 + t] * ssp[i * 64 + j];
        } else {
            v = sb[(k - 512) * 64 + j];
        }
        W1f[idx] = f2bf(v);
    } else if (idx < 45056) {
        const int f = idx - 36864;
        const int e = f & 7, l = (f >> 3) & 63, c = (f >> 9) & 3, s = f >> 11;
        const int k = s * 32 + ((l >> 4) << 3) + e;
        const int j = (c << 4) + (l & 15);
        W2f[f] = f2bf(f2w[j * 64 + k]);
    } else if (idx < 53248) {
        const int f = idx - 45056;
        const int e = f & 7, l = (f >> 3) & 63, c = (f >> 9) & 3, s = f >> 11;
        const int k = s * 32 + ((l >> 4) << 3) + e;
        const int j = (c << 4) + (l & 15);
        WRf[f] = f2bf(reduce_w[j * CIN + k]);
    } else if (idx < 57344) {
        const int f = idx - 53248;
        const int e = f & 7, l = (f >> 3) & 63, c = (f >> 9) & 3, s = f >> 11;
        const int k = s * 32 + ((l >> 4) << 3) + e;
        const int j = (c << 4) + (l & 15);
        WGf[f] = f2bf(g_w[j * 64 + k]);
    } else if (idx < 57600) {
        const int q = (idx - 57344) >> 6, c = idx & 63;
        if (q == 0) cbuf[c] = dw_g[c] * rsqrtf(dw_v[c] + BN_EPS);
        else if (q == 1) {
            float sc = dw_g[c] * rsqrtf(dw_v[c] + BN_EPS);
            cbuf[64 + c] = (dw_b[c] - dw_m[c]) * sc + dw_beta[c];
        } else if (q == 2) cbuf[128 + c] = g_g[c] * rsqrtf(g_v[c] + BN_EPS);
        else {
            float sc = g_g[c] * rsqrtf(g_v[c] + BN_EPS);
            cbuf[192 + c] = (g_b[c] - g_m[c]) * sc + g_beta[c];
        }
    }
}

// ---------------------------------------------------------------------------
// K1: 1x1 conv 128->64 via MFMA. (unchanged from round 3)
// ---------------------------------------------------------------------------
__global__ __launch_bounds__(256) void k_reduce_mfma(
    const float* __restrict__ x, const short* __restrict__ WRf,
    const float* __restrict__ bias, float* __restrict__ out)
{
    __shared__ __align__(16) char smem[34048];
    short* As = (short*)smem;
    float* Osh = (float*)smem;
    const int bid = blockIdx.x;
    const int b = bid >> 5, h0 = (bid & 31) * 2;
    const int tid = threadIdx.x;
    const float* xb = x + (size_t)b * CIN * PLANE + h0 * WW;
#pragma unroll 1
    for (int p = 0; p < 64; ++p) {
        const int idx = tid + (p << 8);
        const int c = idx >> 7, rt = idx & 127;
        const float v = xb[(size_t)c * PLANE + rt];
        const int s = c >> 5, g = (c >> 3) & 3, e = c & 7;
        const int mt = rt >> 4, m = rt & 15;
        As[((mt * 4 + s) * 64 + (((g << 4) | m) ^ (s & 7))) * 8 + e] = f2bf(v);
    }
    __syncthreads();
    const int cw = tid >> 6, l = tid & 63;
    f32x4 acc[8];
#pragma unroll
    for (int i = 0; i < 8; ++i) acc[i] = (f32x4){0.f, 0.f, 0.f, 0.f};
#pragma unroll 1
    for (int s = 0; s < 4; ++s) {
        const short8v bfr = *(const short8v*)&WRf[((s * 4 + cw) * 64 + l) * 8];
        const int lx = l ^ (s & 7);
#pragma unroll
        for (int mt = 0; mt < 8; ++mt) {
            const short8v a = *(const short8v*)&As[((mt * 4 + s) * 64 + lx) * 8];
            acc[mt] = __builtin_amdgcn_mfma_f32_16x16x32_bf16(a, bfr, acc[mt], 0, 0, 0);
        }
    }
    __syncthreads();
    const int j = (cw << 4) + (l & 15);
    const float bj = bias[j];
    const int rb = (l >> 4) << 2;
#pragma unroll
    for (int mt = 0; mt < 8; ++mt)
#pragma unroll
        for (int r = 0; r < 4; ++r)
            Osh[j * 133 + mt * 16 + rb + r] = acc[mt][r] + bj;
    __syncthreads();
    float* ob = out + (size_t)b * CD * PLANE + h0 * WW;
#pragma unroll 1
    for (int p = 0; p < 32; ++p) {
        const int idx = tid + (p << 8);
        const int jj = idx >> 7, rt = idx & 127;
        ob[(size_t)jj * PLANE + rt] = Osh[jj * 133 + rt];
    }
}

// ---------------------------------------------------------------------------
// K2/K5: 7x7 depthwise conv, register-streaming, quarter-plane strips.
// (unchanged from round 6)
// ---------------------------------------------------------------------------
template<bool RESID>
__global__ __launch_bounds__(256) void k_dwconv(
    const float* __restrict__ in, const float* __restrict__ filt,
    const float* __restrict__ sc, const float* __restrict__ shv,
    const float* __restrict__ resid, float* __restrict__ out)
{
    const int bid = blockIdx.x;
    const int b = bid >> 6, c4 = (bid >> 2) & 15, strip = bid & 3;
    const int H0 = strip << 4;
    const int c = c4 * 4 + (threadIdx.x >> 6);
    const int lane = threadIdx.x & 63;
    const size_t pbase = ((size_t)b * CD + c) * PLANE;
    const float* plane = in + pbase;
    const float* wp = filt + c * 49;
    float K[49];
#pragma unroll
    for (int q = 0; q < 49; ++q) K[q] = wp[q];
    const float scl = RESID ? 1.f : sc[c];
    const float shf = shv[c];
    const float* rplane = RESID ? (resid + pbase) : nullptr;
    float* oplane = out + pbase;

    float acc[7] = {0.f, 0.f, 0.f, 0.f, 0.f, 0.f, 0.f};
#pragma unroll
    for (int rr = 0; rr < 22; ++rr) {
        const int ra = H0 + rr - 3;
        float rowv = 0.f;
        if (ra >= 0 && ra < 64) rowv = plane[ra * 64 + lane];
        float sh[7];
        sh[3] = rowv;
#pragma unroll
        for (int d = 1; d <= 3; ++d) {
            float tp = __shfl(rowv, lane + d);
            sh[3 + d] = (lane + d < 64) ? tp : 0.f;
            float tm = __shfl(rowv, lane - d);
            sh[3 - d] = (lane - d >= 0) ? tm : 0.f;
        }
#pragma unroll
        for (int dy = 0; dy < 7; ++dy) {
            const int o = rr - dy;
            if (o >= 0 && o < 16) {
                const int slot = o % 7;
#pragma unroll
                for (int dx = 0; dx < 7; ++dx)
                    acc[slot] = fmaf(sh[dx], K[dy * 7 + dx], acc[slot]);
            }
        }
        const int done = rr - 6;
        if (done >= 0 && done < 16) {
            const int slot = done % 7;
            const int h = H0 + done;
            float val;
            if (RESID) val = acc[slot] + shf + rplane[h * 64 + lane];
            else       val = acc[slot] * scl + shf;
            oplane[h * 64 + lane] = val;
            acc[slot] = 0.f;
        }
    }
}

// ---------------------------------------------------------------------------
// K3: fused KAN + f2 + gate + g-conv + BN, NCHW -> NCHW.
// ROUND 11: round-10's wave-autonomous dataflow (register spline A-frags,
// wave-private LDS pair-pads, zero barriers) + the schedule fix its counters
// demanded (MfmaUtil 7.5 / VALU 26 / occ 27 => exposed L2 latency, VGPR=76
// left no room to pipeline): 22 uniform B-steps (W1f[0..17], W2f[0..1],
// WGf[0..1]) with DEPTH-2 PING-PONG B prefetch (bq[2][4], refill slot s&1
// with step s+2 before consuming step s => ~2 steps = ~400cy issue-to-use),
// DEPTH-4 rolling x prefetch (8 VGPRs, not 32). 64-thread blocks (1 wave,
// 8.7KB LDS), __launch_bounds__(64,3). All indices static via full unroll.
// ---------------------------------------------------------------------------
__global__ __launch_bounds__(64, 3) void k_kan_fused(
    const float* __restrict__ xd, const short* __restrict__ W1f,
    const short* __restrict__ W2f, const short* __restrict__ WGf,
    const float* __restrict__ kb, const float* __restrict__ f2b,
    const float* __restrict__ gs, const float* __restrict__ gsh,
    float* __restrict__ z)
{
    __shared__ unsigned sS[64 * 17];   // silu pairs; reused for y pairs
    __shared__ unsigned sV[64 * 17];   // raw-v pairs
    const int l = threadIdx.x & 63;
    const int hi = l >> 4, m = l & 15;
    const int tg0 = blockIdx.x * 32;
    const int bb = tg0 >> 12, pix0 = tg0 & 4095;
    const float* xb = xd + (size_t)bb * CD * PLANE + pix0;
    float* zb = z + (size_t)bb * CD * PLANE + pix0;

    // per-lane j-tile constants
    float kbj[4], f2bj[4], sj[4], hj[4];
#pragma unroll
    for (int jt = 0; jt < 4; ++jt) {
        const int j = jt * 16 + m;
        kbj[jt] = kb[j]; f2bj[jt] = f2b[j]; sj[jt] = gs[j]; hj[jt] = gsh[j];
    }

    // ---- prologue: B steps 0,1 and x steps 0..3 in flight ----
    short8v bq[2][4];
#pragma unroll
    for (int jt = 0; jt < 4; ++jt)
        bq[0][jt] = *(const short8v*)&W1f[((0 * 4 + jt) * 64 + l) * 8];
#pragma unroll
    for (int jt = 0; jt < 4; ++jt)
        bq[1][jt] = *(const short8v*)&W1f[((1 * 4 + jt) * 64 + l) * 8];
    float xq0[4], xq1[4];
#pragma unroll
    for (int d = 0; d < 4; ++d) {
        xq0[d] = xb[(size_t)(4 * d + hi) * PLANE + m];
        xq1[d] = xb[(size_t)(4 * d + hi) * PLANE + 16 + m];
    }

    f32x4 accA0[4], accA1[4];
#pragma unroll
    for (int jt = 0; jt < 4; ++jt) {
        accA0[jt] = (f32x4){0.f, 0.f, 0.f, 0.f};
        accA1[jt] = (f32x4){0.f, 0.f, 0.f, 0.f};
    }

    // ---- steps 0..15: spline K-steps (A-frags computed in registers) ----
#pragma unroll
    for (int s = 0; s < 16; ++s) {
        short8v cur[4];
#pragma unroll
        for (int jt = 0; jt < 4; ++jt) cur[jt] = bq[s & 1][jt];
        // refill this slot with step s+2 (s+2 <= 17 here => always W1f)
#pragma unroll
        for (int jt = 0; jt < 4; ++jt)
            bq[s & 1][jt] = *(const short8v*)&W1f[(((s + 2) * 4 + jt) * 64 + l) * 8];
        const float v0 = xq0[s & 3], v1 = xq1[s & 3];
        if (s < 12) {   // rolling x refill, 4 steps ahead
            xq0[s & 3] = xb[(size_t)(4 * (s + 4) + hi) * PLANE + m];
            xq1[s & 3] = xb[(size_t)(4 * (s + 4) + hi) * PLANE + 16 + m];
        }
        const int c = 4 * s + hi;
        const float sl0 = v0 * __builtin_amdgcn_rcpf(1.0f + __expf(-v0));
        const float sl1 = v1 * __builtin_amdgcn_rcpf(1.0f + __expf(-v1));
        sS[c * 17 + m] = cvtpk(sl0, sl1);
        sV[c * 17 + m] = cvtpk(v0, v1);
        const short8v a0 = __builtin_bit_cast(short8v, basisD(v0));
        const short8v a1 = __builtin_bit_cast(short8v, basisD(v1));
#pragma unroll
        for (int jt = 0; jt < 4; ++jt) {
            accA0[jt] = __builtin_amdgcn_mfma_f32_16x16x32_bf16(a0, cur[jt], accA0[jt], 0, 0, 0);
            accA1[jt] = __builtin_amdgcn_mfma_f32_16x16x32_bf16(a1, cur[jt], accA1[jt], 0, 0, 0);
        }
    }

    // ---- steps 16,17: silu K-steps (frags from sS); prefetch W2f ----
#pragma unroll
    for (int s2 = 0; s2 < 2; ++s2) {   // global step 16+s2, slot (16+s2)&1 = s2
        short8v cur[4];
#pragma unroll
        for (int jt = 0; jt < 4; ++jt) cur[jt] = bq[s2 & 1][jt];
#pragma unroll
        for (int jt = 0; jt < 4; ++jt)
            bq[s2 & 1][jt] = *(const short8v*)&W2f[((s2 * 4 + jt) * 64 + l) * 8];
        short8v f0, f1;
        gather_frags(sS, s2, hi, m, f0, f1);
#pragma unroll
        for (int jt = 0; jt < 4; ++jt) {
            accA0[jt] = __builtin_amdgcn_mfma_f32_16x16x32_bf16(f0, cur[jt], accA0[jt], 0, 0, 0);
            accA1[jt] = __builtin_amdgcn_mfma_f32_16x16x32_bf16(f1, cur[jt], accA1[jt], 0, 0, 0);
        }
    }

    // ---- steps 18,19: GEMM2 (frags from sV); prefetch WGf ----
    f32x4 accB0[4], accB1[4];
#pragma unroll
    for (int jt = 0; jt < 4; ++jt) {
        accB0[jt] = (f32x4){0.f, 0.f, 0.f, 0.f};
        accB1[jt] = (f32x4){0.f, 0.f, 0.f, 0.f};
    }
#pragma unroll
    for (int s3 = 0; s3 < 2; ++s3) {   // global step 18+s3, slot s3
        short8v cur[4];
#pragma unroll
        for (int jt = 0; jt < 4; ++jt) cur[jt] = bq[s3 & 1][jt];
#pragma unroll
        for (int jt = 0; jt < 4; ++jt)
            bq[s3 & 1][jt] = *(const short8v*)&WGf[((s3 * 4 + jt) * 64 + l) * 8];
        short8v f0, f1;
        gather_frags(sV, s3, hi, m, f0, f1);
#pragma unroll
        for (int jt = 0; jt < 4; ++jt) {
            accB0[jt] = __builtin_amdgcn_mfma_f32_16x16x32_bf16(f0, cur[jt], accB0[jt], 0, 0, 0);
            accB1[jt] = __builtin_amdgcn_mfma_f32_16x16x32_bf16(f1, cur[jt], accB1[jt], 0, 0, 0);
        }
    }

    // ---- gate: y = (x1+kb)*(x2+f2b); stash y pairs into sS ----
    const int rb = hi * 4;   // C-layout row base: row = (l>>4)*4 + r
#pragma unroll
    for (int jt = 0; jt < 4; ++jt)
#pragma unroll
        for (int r = 0; r < 4; ++r) {
            const float ya = (accA0[jt][r] + kbj[jt]) * (accB0[jt][r] + f2bj[jt]);
            const float yb2 = (accA1[jt][r] + kbj[jt]) * (accB1[jt][r] + f2bj[jt]);
            sS[(jt * 16 + m) * 17 + rb + r] = cvtpk(ya, yb2);
        }

    // ---- steps 20,21: GEMM3 (frags from sS = y) ----
    f32x4 acc30[4], acc31[4];
#pragma unroll
    for (int jt = 0; jt < 4; ++jt) {
        acc30[jt] = (f32x4){0.f, 0.f, 0.f, 0.f};
        acc31[jt] = (f32x4){0.f, 0.f, 0.f, 0.f};
    }
#pragma unroll
    for (int s3 = 0; s3 < 2; ++s3) {   // global step 20+s3, slot s3
        short8v cur[4];
#pragma unroll
        for (int jt = 0; jt < 4; ++jt) cur[jt] = bq[s3 & 1][jt];
        short8v f0, f1;
        gather_frags(sS, s3, hi, m, f0, f1);
#pragma unroll
        for (int jt = 0; jt < 4; ++jt) {
            acc30[jt] = __builtin_amdgcn_mfma_f32_16x16x32_bf16(f0, cur[jt], acc30[jt], 0, 0, 0);
            acc31[jt] = __builtin_amdgcn_mfma_f32_16x16x32_bf16(f1, cur[jt], acc31[jt], 0, 0, 0);
        }
    }

    // ---- epilogue: BN + direct NCHW stores (16B contiguous per (jt,tile)) ----
#pragma unroll
    for (int jt = 0; jt < 4; ++jt) {
        const int j = jt * 16 + m;
        f32x4 o0, o1;
#pragma unroll
        for (int r = 0; r < 4; ++r) {
            o0[r] = acc30[jt][r] * sj[jt] + hj[jt];
            o1[r] = acc31[jt][r] * sj[jt] + hj[jt];
        }
        *(f32x4*)&zb[(size_t)j * PLANE + rb] = o0;
        *(f32x4*)&zb[(size_t)j * PLANE + 16 + rb] = o1;
    }
}

// ---------------------------------------------------------------------------
extern "C" void kernel_launch(void* const* d_in, const int* in_sizes, int n_in,
                              void* d_out, int out_size, void* d_ws, size_t ws_size,
                              hipStream_t stream)
{
    (void)in_sizes; (void)n_in; (void)out_size; (void)ws_size;
    const float* x        = (const float*)d_in[0];
    const float* reduce_w = (const float*)d_in[1];
    const float* reduce_b = (const float*)d_in[2];
    const float* dw_w     = (const float*)d_in[3];
    const float* dw_b     = (const float*)d_in[4];
    const float* dw_g     = (const float*)d_in[5];
    const float* dw_beta  = (const float*)d_in[6];
    const float* dw_m     = (const float*)d_in[7];
    const float* dw_v     = (const float*)d_in[8];
    const float* f2_w     = (const float*)d_in[9];
    const float* f2_b     = (const float*)d_in[10];
    const float* coef     = (const float*)d_in[11];
    const float* sbase    = (const float*)d_in[12];
    const float* ssp      = (const float*)d_in[13];
    const float* kbias    = (const float*)d_in[14];
    const float* g_w      = (const float*)d_in[15];
    const float* g_b      = (const float*)d_in[16];
    const float* g_g      = (const float*)d_in[17];
    const float* g_beta   = (const float*)d_in[18];
    const float* g_m      = (const float*)d_in[19];
    const float* g_v      = (const float*)d_in[20];
    const float* dw2_w    = (const float*)d_in[21];
    const float* dw2_b    = (const float*)d_in[22];
    float* out = (float*)d_out;

    const size_t NEL = (size_t)BSZ * CD * PLANE;
    short* W1f = (short*)d_ws;
    short* W2f = W1f + 36864;
    short* WRf = W2f + 8192;
    short* WGf = WRf + 8192;
    float* cbuf = (float*)((char*)d_ws + 115200);
    float* inp = (float*)((char*)d_ws + 131072);
    float* xdb = inp + NEL;
    float* z   = xdb + NEL;

    k_prep<<<225, 256, 0, stream>>>(coef, ssp, sbase, f2_w, reduce_w, g_w,
                                    dw_g, dw_beta, dw_m, dw_v, dw_b,
                                    g_g, g_beta, g_m, g_v, g_b,
                                    W1f, W2f, WRf, WGf, cbuf);
    k_reduce_mfma<<<BSZ * 32, 256, 0, stream>>>(x, WRf, reduce_b, inp);
    k_dwconv<false><<<BSZ * 16 * 4, 256, 0, stream>>>(inp, dw_w, cbuf, cbuf + 64, nullptr, xdb);
    k_kan_fused<<<NPIX / 32, 64, 0, stream>>>(xdb, W1f, W2f, WGf, kbias, f2_b,
                                              cbuf + 128, cbuf + 192, z);
    k_dwconv<true><<<BSZ * 16 * 4, 256, 0, stream>>>(z, dw2_w, nullptr, dw2_b, inp, out);
}